// Round 4
// baseline (2273.366 us; speedup 1.0000x reference)
//
#include <hip/hip_runtime.h>
#include <math.h>

#define B_ 8
#define N_ 16384
#define P_ 512

// f32-element offsets in d_out: [new_xyz | idx | att | ori]
#define OFF_NEWXYZ 0
#define OFF_IDX    12288
#define OFF_ATT    274432
#define OFF_ORI    278528

// ---------------------------------------------------------------------------
// FPS: one 1024-thread block per batch. Writes exact f32 centers directly to
// d_out[0:12288). Bit-exact replication of reference arithmetic (no fp
// contraction: explicit __fsub_rn/__fmul_rn/__fadd_rn; ((x^2+y^2)+z^2) order).
// ---------------------------------------------------------------------------
__global__ __launch_bounds__(1024) void fps_kernel(const float* __restrict__ xyz,
                                                   float* __restrict__ out_newxyz)
{
    const int b = blockIdx.x;
    const int t = threadIdx.x;
    const int lane = t & 63;
    const int wid = t >> 6;
    const float* base = xyz + (size_t)b * N_ * 3;

    float px[16], py[16], pz[16], dd[16];
#pragma unroll
    for (int k = 0; k < 16; ++k) {
        int j = t + k * 1024;
        px[k] = base[j * 3 + 0];
        py[k] = base[j * 3 + 1];
        pz[k] = base[j * 3 + 2];
        dd[k] = __builtin_inff();
    }

    __shared__ float red_d[16];
    __shared__ int   red_i[16];
    __shared__ int   winner[2];

    float lx = base[0], ly = base[1], lz = base[2];
    if (t == 0) {
        int o = b * P_ * 3;
        out_newxyz[o + 0] = lx; out_newxyz[o + 1] = ly; out_newxyz[o + 2] = lz;
    }

    for (int p = 1; p < P_; ++p) {
        float bestd = -1.0f;
        int   besti = 0;
#pragma unroll
        for (int k = 0; k < 16; ++k) {
            float dx = __fsub_rn(px[k], lx);
            float dy = __fsub_rn(py[k], ly);
            float dz = __fsub_rn(pz[k], lz);
            float d2 = __fadd_rn(__fadd_rn(__fmul_rn(dx, dx), __fmul_rn(dy, dy)),
                                 __fmul_rn(dz, dz));
            float nd = fminf(dd[k], d2);
            dd[k] = nd;
            bool gt = nd > bestd;              // strict: lowest k wins ties
            besti = gt ? (t + k * 1024) : besti;
            bestd = gt ? nd : bestd;
        }
        // intra-wave argmax (value desc, index asc on ties)
#pragma unroll
        for (int m = 1; m < 64; m <<= 1) {
            float od = __shfl_xor(bestd, m, 64);
            int   oi = __shfl_xor(besti, m, 64);
            bool take = (od > bestd) || (od == bestd && oi < besti);
            bestd = take ? od : bestd;
            besti = take ? oi : besti;
        }
        if (lane == 0) { red_d[wid] = bestd; red_i[wid] = besti; }
        __syncthreads();
        if (t == 0) {
            float bd = red_d[0]; int bi = red_i[0];
#pragma unroll
            for (int w = 1; w < 16; ++w) {
                float d = red_d[w]; int i = red_i[w];
                if (d > bd || (d == bd && i < bi)) { bd = d; bi = i; }
            }
            winner[p & 1] = bi;
        }
        __syncthreads();
        int wi = winner[p & 1];
        lx = base[wi * 3 + 0];                 // uniform address -> broadcast
        ly = base[wi * 3 + 1];
        lz = base[wi * 3 + 2];
        if (t == 0) {
            int o = (b * P_ + p) * 3;
            out_newxyz[o + 0] = lx; out_newxyz[o + 1] = ly; out_newxyz[o + 2] = lz;
        }
    }
}

// ---------------------------------------------------------------------------
// Fused ball-query + per-center MLP. One 256-thread block per center.
// Reads f32 centers from d_out[0:12288) (stream-ordered after fps).
// Writes f32 idx / att / ori.
// ---------------------------------------------------------------------------
__global__ __launch_bounds__(256) void mlp_kernel(
    const float* __restrict__ xyz,
    const float* __restrict__ centers,     // = d_out + OFF_NEWXYZ
    const float* __restrict__ w0, const float* __restrict__ b0,
    const float* __restrict__ w1, const float* __restrict__ b1,
    const float* __restrict__ w2, const float* __restrict__ b2,
    const float* __restrict__ w3, const float* __restrict__ b3,
    const float* __restrict__ w4, const float* __restrict__ b4,
    const float* __restrict__ attw, const float* __restrict__ attb,
    const float* __restrict__ oriw, const float* __restrict__ orib,
    float* __restrict__ out_idx,
    float* __restrict__ out_att,
    float* __restrict__ out_ori)
{
    const int bp = blockIdx.x;
    const int b = bp >> 9;
    const int tid = threadIdx.x;
    const int lane = tid & 63;
    const int w = tid >> 6;
    const float* base = xyz + (size_t)b * N_ * 3;

    __shared__ __attribute__((aligned(16))) float h0s[64 * 68];   // 17.4 KB (aliased as red[16][256])
    __shared__ __attribute__((aligned(16))) float h1s[64 * 132];  // 33.8 KB
    __shared__ float qx[64], qy[64], qz[64];
    __shared__ float vmaxs[256];
    __shared__ float h3s[128];
    __shared__ float h4s[64];
    __shared__ int s_hits[4][64];
    __shared__ int s_cnt[4];
    __shared__ int s_sel[64];
    float* red = h0s;  // 16*256 = 4096 <= 64*68

    const float cx = centers[bp * 3 + 0];
    const float cy = centers[bp * 3 + 1];
    const float cz = centers[bp * 3 + 2];

    // --- ball query: each wave scans its quarter [w*4096,(w+1)*4096) ---
    {
        const int qbase = w * 4096;
        int cnt = 0;
        for (int chunk = 0; chunk < 64 && cnt < 64; ++chunk) {
            int j = qbase + chunk * 64 + lane;
            float x = base[j * 3 + 0];
            float y = base[j * 3 + 1];
            float z = base[j * 3 + 2];
            float dx = __fsub_rn(cx, x);
            float dy = __fsub_rn(cy, y);
            float dz = __fsub_rn(cz, z);
            float d2 = __fadd_rn(__fadd_rn(__fmul_rn(dx, dx), __fmul_rn(dy, dy)),
                                 __fmul_rn(dz, dz));
            bool in = d2 < 4.0f;
            unsigned long long m = __ballot(in);
            if (in) {
                int pos = cnt + (int)__popcll(m & ((1ULL << lane) - 1ULL));
                if (pos < 64) s_hits[w][pos] = j;
            }
            cnt += (int)__popcll(m);
        }
        if (lane == 0) s_cnt[w] = cnt;
    }
    __syncthreads();
    // --- ordered merge: quarter concatenation = global ascending index ---
    if (tid < 64) {
        int off = 0, sel = -1;
#pragma unroll
        for (int ww = 0; ww < 4; ++ww) {
            int c = s_cnt[ww];
            int r = tid - off;        // r <= 63 always, so s_hits access is in-bounds
            if (sel < 0 && r >= 0 && r < c) sel = s_hits[ww][r];
            off += c;
        }
        s_sel[tid] = sel;
    }
    __syncthreads();

    if (tid < 64) {
        int sel = s_sel[tid];
        int pad = s_sel[0];          // total hits >= 1 (center is itself a point)
        if (sel < 0) sel = pad;
        sel = min(sel, N_ - 1);
        out_idx[bp * 64 + tid] = (float)sel;
        // gather + normalize
        const float* pp = base + (size_t)sel * 3;
        qx[tid] = (pp[0] - cx) * 0.5f;
        qy[tid] = (pp[1] - cy) * 0.5f;
        qz[tid] = (pp[2] - cz) * 0.5f;
    }
    __syncthreads();

    // B: h0 = relu(q @ w0 + b0)  (64x64)
#pragma unroll
    for (int k = 0; k < 16; ++k) {
        int o = tid + k * 256;
        int s = o >> 6, d = o & 63;
        float v = b0[d] + qx[s] * w0[d] + qy[s] * w0[64 + d] + qz[s] * w0[128 + d];
        h0s[s * 68 + d] = fmaxf(v, 0.0f);
    }
    __syncthreads();

    const int ts = tid >> 4, td = tid & 15;

    // C: h1 = relu(h0 @ w1 + b1)  (64x128); thread tile 4 rows x 8 cols
    {
        const int d0 = td * 8;
        float acc[4][8];
#pragma unroll
        for (int j = 0; j < 8; ++j) {
            float bv = b1[d0 + j];
#pragma unroll
            for (int r = 0; r < 4; ++r) acc[r][j] = bv;
        }
        for (int cb = 0; cb < 64; cb += 4) {
            float a[4][4];
#pragma unroll
            for (int r = 0; r < 4; ++r) {
                float4 t4 = *(const float4*)&h0s[(ts + 16 * r) * 68 + cb];
                a[r][0] = t4.x; a[r][1] = t4.y; a[r][2] = t4.z; a[r][3] = t4.w;
            }
#pragma unroll
            for (int cc = 0; cc < 4; ++cc) {
                const float* wr = w1 + (cb + cc) * 128 + d0;
                float4 wA = *(const float4*)wr;
                float4 wB = *(const float4*)(wr + 4);
                float wv[8] = {wA.x, wA.y, wA.z, wA.w, wB.x, wB.y, wB.z, wB.w};
#pragma unroll
                for (int r = 0; r < 4; ++r)
#pragma unroll
                    for (int j = 0; j < 8; ++j)
                        acc[r][j] = fmaf(a[r][cc], wv[j], acc[r][j]);
            }
        }
#pragma unroll
        for (int r = 0; r < 4; ++r)
#pragma unroll
            for (int j = 0; j < 8; ++j)
                h1s[(ts + 16 * r) * 132 + d0 + j] = fmaxf(acc[r][j], 0.0f);
    }
    __syncthreads();

    // D: h2 = h1 @ w2 + b2, per-thread partial maxpool over s
    {
        const int d0 = td * 16;
        float acc[4][16];
#pragma unroll
        for (int j = 0; j < 16; ++j) {
            float bv = b2[d0 + j];
#pragma unroll
            for (int r = 0; r < 4; ++r) acc[r][j] = bv;
        }
        for (int cb = 0; cb < 128; cb += 4) {
            float a[4][4];
#pragma unroll
            for (int r = 0; r < 4; ++r) {
                float4 t4 = *(const float4*)&h1s[(ts + 16 * r) * 132 + cb];
                a[r][0] = t4.x; a[r][1] = t4.y; a[r][2] = t4.z; a[r][3] = t4.w;
            }
#pragma unroll
            for (int cc = 0; cc < 4; ++cc) {
                const float* wr = w2 + (cb + cc) * 256 + d0;
                float4 wA = *(const float4*)wr;
                float4 wB = *(const float4*)(wr + 4);
                float4 wC = *(const float4*)(wr + 8);
                float4 wD = *(const float4*)(wr + 12);
                float wv[16] = {wA.x, wA.y, wA.z, wA.w, wB.x, wB.y, wB.z, wB.w,
                                wC.x, wC.y, wC.z, wC.w, wD.x, wD.y, wD.z, wD.w};
#pragma unroll
                for (int r = 0; r < 4; ++r)
#pragma unroll
                    for (int j = 0; j < 16; ++j)
                        acc[r][j] = fmaf(a[r][cc], wv[j], acc[r][j]);
            }
        }
#pragma unroll
        for (int j = 0; j < 16; ++j) {
            float v = fmaxf(fmaxf(acc[0][j], acc[1][j]), fmaxf(acc[2][j], acc[3][j]));
            red[ts * 256 + d0 + j] = v;
        }
    }
    __syncthreads();
    {
        float m = red[tid];
#pragma unroll
        for (int ww = 1; ww < 16; ++ww) m = fmaxf(m, red[ww * 256 + tid]);
        vmaxs[tid] = fmaxf(m, 0.0f);   // relu(max) == max(relu): exact
    }
    __syncthreads();

    // E: conv3 (256->128), conv4 (128->64), heads
    if (tid < 128) {
        float acc = b3[tid];
        for (int c = 0; c < 256; ++c) acc = fmaf(vmaxs[c], w3[c * 128 + tid], acc);
        h3s[tid] = fmaxf(acc, 0.0f);
    }
    __syncthreads();
    if (tid < 64) {
        float acc = b4[tid];
        for (int c = 0; c < 128; ++c) acc = fmaf(h3s[c], w4[c * 64 + tid], acc);
        h4s[tid] = fmaxf(acc, 0.0f);
    }
    __syncthreads();
    if (tid < 64) {
        float h = h4s[tid];
        float pa  = h * attw[tid];
        float pox = h * oriw[tid * 2 + 0];
        float poy = h * oriw[tid * 2 + 1];
#pragma unroll
        for (int m = 1; m < 64; m <<= 1) {
            pa  += __shfl_xor(pa, m, 64);
            pox += __shfl_xor(pox, m, 64);
            poy += __shfl_xor(poy, m, 64);
        }
        if (tid == 0) {
            float z = pa + attb[0];
            float att = fmaxf(z, 0.0f) + log1pf(expf(-fabsf(z)));   // softplus
            float ox = pox + orib[0], oy = poy + orib[1];
            float n = sqrtf(fmaxf(ox * ox + oy * oy, 1e-8f));
            ox /= n; oy /= n;
            out_att[bp] = att;
            out_ori[bp] = atan2f(oy, ox);
        }
    }
}

// ---------------------------------------------------------------------------
extern "C" void kernel_launch(void* const* d_in, const int* in_sizes, int n_in,
                              void* d_out, int out_size, void* d_ws, size_t ws_size,
                              hipStream_t stream)
{
    const float* xyz  = (const float*)d_in[0];
    const float* w0   = (const float*)d_in[1];
    const float* b0   = (const float*)d_in[2];
    const float* w1   = (const float*)d_in[3];
    const float* b1   = (const float*)d_in[4];
    const float* w2   = (const float*)d_in[5];
    const float* b2   = (const float*)d_in[6];
    const float* w3   = (const float*)d_in[7];
    const float* b3   = (const float*)d_in[8];
    const float* w4   = (const float*)d_in[9];
    const float* b4   = (const float*)d_in[10];
    const float* attw = (const float*)d_in[11];
    const float* attb = (const float*)d_in[12];
    const float* oriw = (const float*)d_in[13];
    const float* orib = (const float*)d_in[14];

    float* out = (float*)d_out;                 // FLOAT32 output buffer
    float* out_newxyz = out + OFF_NEWXYZ;
    float* out_idx    = out + OFF_IDX;
    float* out_att    = out + OFF_ATT;
    float* out_ori    = out + OFF_ORI;

    fps_kernel<<<dim3(B_), dim3(1024), 0, stream>>>(xyz, out_newxyz);
    mlp_kernel<<<dim3(B_ * P_), dim3(256), 0, stream>>>(
        xyz, out_newxyz,
        w0, b0, w1, b1, w2, b2, w3, b3, w4, b4,
        attw, attb, oriw, orib, out_idx, out_att, out_ori);
}

// Round 7
// 2082.653 us; speedup vs baseline: 1.0916x; 1.0916x over previous
//
#include <hip/hip_runtime.h>
#include <math.h>

#define B_ 8
#define N_ 16384
#define P_ 512

// f32-element offsets in d_out: [new_xyz | idx | att | ori]
#define OFF_NEWXYZ 0
#define OFF_IDX    12288
#define OFF_ATT    274432
#define OFF_ORI    278528

// ---------------------------------------------------------------------------
// FPS v2: one 512-thread block per batch, 32 pts/thread in registers.
// Per iteration: k-loop (exact dist + dd update + argmax w/ coord carry via
// cndmask), wave butterfly carrying (d,i,x,y,z), ONE barrier, all-thread
// 8-entry LDS reduce (double-buffered slots -> no 2nd barrier), no dependent
// global loads. Bit-exact reference arithmetic for all discrete decisions.
// ---------------------------------------------------------------------------
__global__ __launch_bounds__(512, 2) void fps_kernel(const float* __restrict__ xyz,
                                                     float* __restrict__ out_newxyz)
{
    const int b = blockIdx.x;
    const int t = threadIdx.x;
    const int lane = t & 63;
    const int wid = t >> 6;                     // 0..7
    const float* base = xyz + (size_t)b * N_ * 3;

    float px[32], py[32], pz[32], dd[32];
#pragma unroll
    for (int k = 0; k < 32; ++k) {
        int j = t + k * 512;
        px[k] = base[j * 3 + 0];
        py[k] = base[j * 3 + 1];
        pz[k] = base[j * 3 + 2];
        dd[k] = __builtin_inff();
    }

    __shared__ float s_d[2][8], s_x[2][8], s_y[2][8], s_z[2][8];
    __shared__ int   s_i[2][8];

    float lx = base[0], ly = base[1], lz = base[2];
    if (t == 0) {
        int o = b * P_ * 3;
        out_newxyz[o + 0] = lx; out_newxyz[o + 1] = ly; out_newxyz[o + 2] = lz;
    }

#pragma unroll 1
    for (int p = 1; p < P_; ++p) {
        float bestd = -1.0f;
        int   bestk = 0;
        float bx = 0.0f, by = 0.0f, bz = 0.0f;
#pragma unroll
        for (int k = 0; k < 32; ++k) {
            float dx = __fsub_rn(px[k], lx);
            float dy = __fsub_rn(py[k], ly);
            float dz = __fsub_rn(pz[k], lz);
            float d2 = __fadd_rn(__fadd_rn(__fmul_rn(dx, dx), __fmul_rn(dy, dy)),
                                 __fmul_rn(dz, dz));
            float nd = fminf(dd[k], d2);
            dd[k] = nd;
            bool gt = nd > bestd;              // strict: lowest k (=lowest idx) on ties
            bestd = gt ? nd : bestd;
            bestk = gt ? k : bestk;            // literal k -> cndmask, no reg-array index
            bx = gt ? px[k] : bx;              // static index: stays in registers
            by = gt ? py[k] : by;
            bz = gt ? pz[k] : bz;
        }
        int besti = t + bestk * 512;           // global point index

        // intra-wave butterfly argmax carrying (d,i,x,y,z); value desc, idx asc
#pragma unroll
        for (int m = 1; m < 64; m <<= 1) {
            float od = __shfl_xor(bestd, m, 64);
            int   oi = __shfl_xor(besti, m, 64);
            float ox = __shfl_xor(bx, m, 64);
            float oy = __shfl_xor(by, m, 64);
            float oz = __shfl_xor(bz, m, 64);
            bool take = (od > bestd) || (od == bestd && oi < besti);
            bestd = take ? od : bestd;
            besti = take ? oi : besti;
            bx = take ? ox : bx;
            by = take ? oy : by;
            bz = take ? oz : bz;
        }
        const int pb = p & 1;
        if (lane == 0) {
            s_d[pb][wid] = bestd; s_i[pb][wid] = besti;
            s_x[pb][wid] = bx;    s_y[pb][wid] = by;    s_z[pb][wid] = bz;
        }
        __syncthreads();
        // all threads redundantly reduce the 8 wave candidates (broadcast reads)
        float bd = s_d[pb][0]; int bi = s_i[pb][0]; int bw = 0;
#pragma unroll
        for (int w = 1; w < 8; ++w) {
            float d = s_d[pb][w]; int i = s_i[pb][w];
            bool take = (d > bd) || (d == bd && i < bi);
            bd = take ? d : bd;
            bi = take ? i : bi;
            bw = take ? w : bw;
        }
        lx = s_x[pb][bw]; ly = s_y[pb][bw]; lz = s_z[pb][bw];   // LDS, not reg array
        if (t == 0) {
            int o = (b * P_ + p) * 3;
            out_newxyz[o + 0] = lx; out_newxyz[o + 1] = ly; out_newxyz[o + 2] = lz;
        }
        // next iteration writes slot (p+1)&1: race-free with this iteration's
        // readers of slot p&1 because both are separated by the single barrier.
    }
}

// ---------------------------------------------------------------------------
// Fused ball-query + per-center MLP. One 256-thread block per center.
// Reads f32 centers from d_out[0:12288) (stream-ordered after fps).
// Writes f32 idx / att / ori.  (UNCHANGED from passing round-4 kernel.)
// ---------------------------------------------------------------------------
__global__ __launch_bounds__(256) void mlp_kernel(
    const float* __restrict__ xyz,
    const float* __restrict__ centers,     // = d_out + OFF_NEWXYZ
    const float* __restrict__ w0, const float* __restrict__ b0,
    const float* __restrict__ w1, const float* __restrict__ b1,
    const float* __restrict__ w2, const float* __restrict__ b2,
    const float* __restrict__ w3, const float* __restrict__ b3,
    const float* __restrict__ w4, const float* __restrict__ b4,
    const float* __restrict__ attw, const float* __restrict__ attb,
    const float* __restrict__ oriw, const float* __restrict__ orib,
    float* __restrict__ out_idx,
    float* __restrict__ out_att,
    float* __restrict__ out_ori)
{
    const int bp = blockIdx.x;
    const int b = bp >> 9;
    const int tid = threadIdx.x;
    const int lane = tid & 63;
    const int w = tid >> 6;
    const float* base = xyz + (size_t)b * N_ * 3;

    __shared__ __attribute__((aligned(16))) float h0s[64 * 68];   // 17.4 KB (aliased as red[16][256])
    __shared__ __attribute__((aligned(16))) float h1s[64 * 132];  // 33.8 KB
    __shared__ float qx[64], qy[64], qz[64];
    __shared__ float vmaxs[256];
    __shared__ float h3s[128];
    __shared__ float h4s[64];
    __shared__ int s_hits[4][64];
    __shared__ int s_cnt[4];
    __shared__ int s_sel[64];
    float* red = h0s;  // 16*256 = 4096 <= 64*68

    const float cx = centers[bp * 3 + 0];
    const float cy = centers[bp * 3 + 1];
    const float cz = centers[bp * 3 + 2];

    // --- ball query: each wave scans its quarter [w*4096,(w+1)*4096) ---
    {
        const int qbase = w * 4096;
        int cnt = 0;
        for (int chunk = 0; chunk < 64 && cnt < 64; ++chunk) {
            int j = qbase + chunk * 64 + lane;
            float x = base[j * 3 + 0];
            float y = base[j * 3 + 1];
            float z = base[j * 3 + 2];
            float dx = __fsub_rn(cx, x);
            float dy = __fsub_rn(cy, y);
            float dz = __fsub_rn(cz, z);
            float d2 = __fadd_rn(__fadd_rn(__fmul_rn(dx, dx), __fmul_rn(dy, dy)),
                                 __fmul_rn(dz, dz));
            bool in = d2 < 4.0f;
            unsigned long long m = __ballot(in);
            if (in) {
                int pos = cnt + (int)__popcll(m & ((1ULL << lane) - 1ULL));
                if (pos < 64) s_hits[w][pos] = j;
            }
            cnt += (int)__popcll(m);
        }
        if (lane == 0) s_cnt[w] = cnt;
    }
    __syncthreads();
    // --- ordered merge: quarter concatenation = global ascending index ---
    if (tid < 64) {
        int off = 0, sel = -1;
#pragma unroll
        for (int ww = 0; ww < 4; ++ww) {
            int c = s_cnt[ww];
            int r = tid - off;        // r <= 63 always, so s_hits access is in-bounds
            if (sel < 0 && r >= 0 && r < c) sel = s_hits[ww][r];
            off += c;
        }
        s_sel[tid] = sel;
    }
    __syncthreads();

    if (tid < 64) {
        int sel = s_sel[tid];
        int pad = s_sel[0];          // total hits >= 1 (center is itself a point)
        if (sel < 0) sel = pad;
        sel = min(sel, N_ - 1);
        out_idx[bp * 64 + tid] = (float)sel;
        // gather + normalize
        const float* pp = base + (size_t)sel * 3;
        qx[tid] = (pp[0] - cx) * 0.5f;
        qy[tid] = (pp[1] - cy) * 0.5f;
        qz[tid] = (pp[2] - cz) * 0.5f;
    }
    __syncthreads();

    // B: h0 = relu(q @ w0 + b0)  (64x64)
#pragma unroll
    for (int k = 0; k < 16; ++k) {
        int o = tid + k * 256;
        int s = o >> 6, d = o & 63;
        float v = b0[d] + qx[s] * w0[d] + qy[s] * w0[64 + d] + qz[s] * w0[128 + d];
        h0s[s * 68 + d] = fmaxf(v, 0.0f);
    }
    __syncthreads();

    const int ts = tid >> 4, td = tid & 15;

    // C: h1 = relu(h0 @ w1 + b1)  (64x128); thread tile 4 rows x 8 cols
    {
        const int d0 = td * 8;
        float acc[4][8];
#pragma unroll
        for (int j = 0; j < 8; ++j) {
            float bv = b1[d0 + j];
#pragma unroll
            for (int r = 0; r < 4; ++r) acc[r][j] = bv;
        }
        for (int cb = 0; cb < 64; cb += 4) {
            float a[4][4];
#pragma unroll
            for (int r = 0; r < 4; ++r) {
                float4 t4 = *(const float4*)&h0s[(ts + 16 * r) * 68 + cb];
                a[r][0] = t4.x; a[r][1] = t4.y; a[r][2] = t4.z; a[r][3] = t4.w;
            }
#pragma unroll
            for (int cc = 0; cc < 4; ++cc) {
                const float* wr = w1 + (cb + cc) * 128 + d0;
                float4 wA = *(const float4*)wr;
                float4 wB = *(const float4*)(wr + 4);
                float wv[8] = {wA.x, wA.y, wA.z, wA.w, wB.x, wB.y, wB.z, wB.w};
#pragma unroll
                for (int r = 0; r < 4; ++r)
#pragma unroll
                    for (int j = 0; j < 8; ++j)
                        acc[r][j] = fmaf(a[r][cc], wv[j], acc[r][j]);
            }
        }
#pragma unroll
        for (int r = 0; r < 4; ++r)
#pragma unroll
            for (int j = 0; j < 8; ++j)
                h1s[(ts + 16 * r) * 132 + d0 + j] = fmaxf(acc[r][j], 0.0f);
    }
    __syncthreads();

    // D: h2 = h1 @ w2 + b2, per-thread partial maxpool over s
    {
        const int d0 = td * 16;
        float acc[4][16];
#pragma unroll
        for (int j = 0; j < 16; ++j) {
            float bv = b2[d0 + j];
#pragma unroll
            for (int r = 0; r < 4; ++r) acc[r][j] = bv;
        }
        for (int cb = 0; cb < 128; cb += 4) {
            float a[4][4];
#pragma unroll
            for (int r = 0; r < 4; ++r) {
                float4 t4 = *(const float4*)&h1s[(ts + 16 * r) * 132 + cb];
                a[r][0] = t4.x; a[r][1] = t4.y; a[r][2] = t4.z; a[r][3] = t4.w;
            }
#pragma unroll
            for (int cc = 0; cc < 4; ++cc) {
                const float* wr = w2 + (cb + cc) * 256 + d0;
                float4 wA = *(const float4*)wr;
                float4 wB = *(const float4*)(wr + 4);
                float4 wC = *(const float4*)(wr + 8);
                float4 wD = *(const float4*)(wr + 12);
                float wv[16] = {wA.x, wA.y, wA.z, wA.w, wB.x, wB.y, wB.z, wB.w,
                                wC.x, wC.y, wC.z, wC.w, wD.x, wD.y, wD.z, wD.w};
#pragma unroll
                for (int r = 0; r < 4; ++r)
#pragma unroll
                    for (int j = 0; j < 16; ++j)
                        acc[r][j] = fmaf(a[r][cc], wv[j], acc[r][j]);
            }
        }
#pragma unroll
        for (int j = 0; j < 16; ++j) {
            float v = fmaxf(fmaxf(acc[0][j], acc[1][j]), fmaxf(acc[2][j], acc[3][j]));
            red[ts * 256 + d0 + j] = v;
        }
    }
    __syncthreads();
    {
        float m = red[tid];
#pragma unroll
        for (int ww = 1; ww < 16; ++ww) m = fmaxf(m, red[ww * 256 + tid]);
        vmaxs[tid] = fmaxf(m, 0.0f);   // relu(max) == max(relu): exact
    }
    __syncthreads();

    // E: conv3 (256->128), conv4 (128->64), heads
    if (tid < 128) {
        float acc = b3[tid];
        for (int c = 0; c < 256; ++c) acc = fmaf(vmaxs[c], w3[c * 128 + tid], acc);
        h3s[tid] = fmaxf(acc, 0.0f);
    }
    __syncthreads();
    if (tid < 64) {
        float acc = b4[tid];
        for (int c = 0; c < 128; ++c) acc = fmaf(h3s[c], w4[c * 64 + tid], acc);
        h4s[tid] = fmaxf(acc, 0.0f);
    }
    __syncthreads();
    if (tid < 64) {
        float h = h4s[tid];
        float pa  = h * attw[tid];
        float pox = h * oriw[tid * 2 + 0];
        float poy = h * oriw[tid * 2 + 1];
#pragma unroll
        for (int m = 1; m < 64; m <<= 1) {
            pa  += __shfl_xor(pa, m, 64);
            pox += __shfl_xor(pox, m, 64);
            poy += __shfl_xor(poy, m, 64);
        }
        if (tid == 0) {
            float z = pa + attb[0];
            float att = fmaxf(z, 0.0f) + log1pf(expf(-fabsf(z)));   // softplus
            float ox = pox + orib[0], oy = poy + orib[1];
            float n = sqrtf(fmaxf(ox * ox + oy * oy, 1e-8f));
            ox /= n; oy /= n;
            out_att[bp] = att;
            out_ori[bp] = atan2f(oy, ox);
        }
    }
}

// ---------------------------------------------------------------------------
extern "C" void kernel_launch(void* const* d_in, const int* in_sizes, int n_in,
                              void* d_out, int out_size, void* d_ws, size_t ws_size,
                              hipStream_t stream)
{
    const float* xyz  = (const float*)d_in[0];
    const float* w0   = (const float*)d_in[1];
    const float* b0   = (const float*)d_in[2];
    const float* w1   = (const float*)d_in[3];
    const float* b1   = (const float*)d_in[4];
    const float* w2   = (const float*)d_in[5];
    const float* b2   = (const float*)d_in[6];
    const float* w3   = (const float*)d_in[7];
    const float* b3   = (const float*)d_in[8];
    const float* w4   = (const float*)d_in[9];
    const float* b4   = (const float*)d_in[10];
    const float* attw = (const float*)d_in[11];
    const float* attb = (const float*)d_in[12];
    const float* oriw = (const float*)d_in[13];
    const float* orib = (const float*)d_in[14];

    float* out = (float*)d_out;                 // FLOAT32 output buffer
    float* out_newxyz = out + OFF_NEWXYZ;
    float* out_idx    = out + OFF_IDX;
    float* out_att    = out + OFF_ATT;
    float* out_ori    = out + OFF_ORI;

    fps_kernel<<<dim3(B_), dim3(512), 0, stream>>>(xyz, out_newxyz);
    mlp_kernel<<<dim3(B_ * P_), dim3(256), 0, stream>>>(
        xyz, out_newxyz,
        w0, b0, w1, b1, w2, b2, w3, b3, w4, b4,
        attw, attb, oriw, orib, out_idx, out_att, out_ori);
}